// Round 17
// baseline (222.310 us; speedup 1.0000x reference)
//
#include <hip/hip_runtime.h>
#include <hip/hip_bf16.h>

// Encoder: B=4, S=2048, D=256, H=8, DK=32, DFF=1024, fp32 in/out.
// bf16 pipeline. Fixed-base softmax (scores>=0: ReLU'd q,k), l via
// ones-MFMA. Attn: K LDS dbuf + V direct from L2 + native v_exp (R15).
// GEMM: BM=128/BN=64, wave 64x32 (read:mfma 0.75), dbuf; N=256 GEMMs
// split-K=2 + fused relu+add+LN combine.

#define MROWS 8192   // B*S
#define DMODEL 256
#define SEQ 2048
#define LN_EPS 1e-5f

typedef float f32x4 __attribute__((ext_vector_type(4)));
typedef unsigned int u32x4 __attribute__((ext_vector_type(4)));

__device__ __forceinline__ unsigned pk2(float lo, float hi) {
  union { __hip_bfloat162 h; unsigned u; } c;
  c.h = __float22bfloat162_rn(make_float2(lo, hi));
  return c.u;
}
__device__ __forceinline__ unsigned short bf1(float f) {
  union { __hip_bfloat16 h; unsigned short u; } c;
  c.h = __float2bfloat16(f);
  return c.u;
}
// native 2^x: single v_exp_f32
__device__ __forceinline__ float fexp2(float x) {
  return __builtin_amdgcn_exp2f(x);
}

__device__ __forceinline__ f32x4 mfma_bf16(u32x4 a, u32x4 b, f32x4 c) {
  asm volatile("v_mfma_f32_16x16x32_bf16 %0, %1, %2, %0"
               : "+v"(c) : "v"(a), "v"(b));
  return c;
}
// zero-dest form: separate dest, shared read-only zero quad (no RMW copy)
__device__ __forceinline__ f32x4 mfma_bf16_z(u32x4 a, u32x4 b,
                                             const f32x4& z) {
  f32x4 d;
  asm volatile("v_mfma_f32_16x16x32_bf16 %0, %1, %2, %3"
               : "=v"(d) : "v"(a), "v"(b), "v"(z));
  return d;
}

__device__ __forceinline__ void gload_lds16(const void* g, void* l) {
  __builtin_amdgcn_global_load_lds(
      (const __attribute__((address_space(1))) void*)g,
      (__attribute__((address_space(3))) void*)l, 16, 0, 0);
}

// ---------------- fp32 -> bf16 batch convert ----------------
struct CvtArgs {
  const float* s[13];
  unsigned short* d[13];
  int n4[13];
};
__global__ __launch_bounds__(256) void cvt_kernel(CvtArgs a) {
  const int y = blockIdx.y;
  const int n4 = a.n4[y];
  const float4* src = (const float4*)a.s[y];
  unsigned short* dst = a.d[y];
  for (int i = blockIdx.x * 256 + threadIdx.x; i < n4; i += 256 * 256) {
    float4 v = src[i];
    uint2 o;
    o.x = pk2(v.x, v.y);
    o.y = pk2(v.z, v.w);
    *(uint2*)(dst + (size_t)i * 4) = o;
  }
}

// ---------------- bf16 MFMA GEMM: relu(A @ W^T) (+res) ----------------
// 256 threads, 4 waves (2m x 2n), block 128x64, wave 64x32 (acc 4x2),
// BK=64, dbuf. Per K-tile: 12 ds_read_b128 : 16 MFMA.
// splitk: grid doubled, lid&1 = K-slice, raw fp32 partial -> outP0/P1.
// Fused-QKV epilogue: n0<256 -> outB (bscale), [256,512) -> outB2,
// >=512 -> outVT (V^T [b*8+h][d][s]). XCD-swizzled 1D grid.
__global__ __launch_bounds__(256) void gemm_bf16_kernel(
    const unsigned short* __restrict__ A, const unsigned short* __restrict__ W,
    const float* __restrict__ res, float* __restrict__ outF,
    unsigned short* __restrict__ outB, unsigned short* __restrict__ outB2,
    unsigned short* __restrict__ outVT, float* __restrict__ outP0,
    float* __restrict__ outP1, float bscale, int N, int K, int ntx,
    int splitk) {
  __shared__ alignas(16) unsigned short As[2][128 * 64];  // 16 KB each
  __shared__ alignas(16) unsigned short Ws[2][64 * 64];   // 8 KB each
  const int tid = threadIdx.x;
  const int w = tid >> 6, lane = tid & 63;
  const int lq = lane & 15, kg = lane >> 4;
  const int wm = w >> 1, wn = w & 1;
  const int nwg = gridDim.x, cpx = nwg >> 3, bid = blockIdx.x;
  int lid = (bid & 7) * cpx + (bid >> 3);
  int kslice = 0;
  if (splitk) { kslice = lid & 1; lid >>= 1; }
  const int m0 = (lid / ntx) * 128, n0 = (lid % ntx) * 64;
  const int klen = splitk ? (K >> 1) : K;
  const unsigned short* Ab = A + (size_t)kslice * (K >> 1);
  const unsigned short* Wb = W + (size_t)kslice * (K >> 1);

  f32x4 acc[4][2] = {};

  auto STAGE = [&](int buf, int k0) {
#pragma unroll
    for (int i = 0; i < 4; i++) {  // A: 128 rows x 8 slots
      const int li = i * 256 + tid;
      const int row = li >> 3, sl = (li & 7) ^ (row & 7);
      gload_lds16(Ab + (size_t)(m0 + row) * K + k0 + sl * 8,
                  (char*)As[buf] + (i * 256 + (tid & ~63)) * 16);
    }
#pragma unroll
    for (int i = 0; i < 2; i++) {  // W: 64 rows x 8 slots
      const int li = i * 256 + tid;
      const int row = li >> 3, sl = (li & 7) ^ (row & 7);
      gload_lds16(Wb + (size_t)(n0 + row) * K + k0 + sl * 8,
                  (char*)Ws[buf] + (i * 256 + (tid & ~63)) * 16);
    }
  };

  const int nt = klen >> 6;
  STAGE(0, 0);
  for (int t = 0; t < nt; t++) {
    __syncthreads();  // drains vmcnt: buf[t&1] ready
    if (t + 1 < nt) STAGE((t + 1) & 1, (t + 1) << 6);
    const unsigned short* as = As[t & 1];
    const unsigned short* wsb = Ws[t & 1];
#pragma unroll
    for (int kk = 0; kk < 2; kk++) {
      const int sl = (((kk * 4 + kg) ^ (lq & 7)) << 3);
      u32x4 af[4], bfr[2];
#pragma unroll
      for (int mi = 0; mi < 4; mi++)
        af[mi] = *(const u32x4*)&as[((wm * 64 + mi * 16 + lq) << 6) + sl];
#pragma unroll
      for (int nj = 0; nj < 2; nj++)
        bfr[nj] = *(const u32x4*)&wsb[((wn * 32 + nj * 16 + lq) << 6) + sl];
      __builtin_amdgcn_s_setprio(1);
#pragma unroll
      for (int mi = 0; mi < 4; mi++)
#pragma unroll
        for (int nj = 0; nj < 2; nj++)
          acc[mi][nj] = mfma_bf16(af[mi], bfr[nj], acc[mi][nj]);
      __builtin_amdgcn_s_setprio(0);
    }
  }

  // Epilogue: D row = kg*4+r, col = lq per 16x16 frag.
  if (splitk) {  // raw fp32 partial (no relu, no res)
    float* P = kslice ? outP1 : outP0;
#pragma unroll
    for (int mi = 0; mi < 4; mi++) {
      const int m = m0 + wm * 64 + mi * 16 + kg * 4;
#pragma unroll
      for (int nj = 0; nj < 2; nj++) {
        const int n = n0 + wn * 32 + nj * 16 + lq;
#pragma unroll
        for (int r = 0; r < 4; r++)
          P[(size_t)(m + r) * N + n] = acc[mi][nj][r];
      }
    }
  } else if (outVT && n0 >= 512) {  // V^T path (fused QKV)
#pragma unroll
    for (int mi = 0; mi < 4; mi++) {
      const int mb = m0 + wm * 64 + mi * 16 + kg * 4;
      const int bq = mb >> 11, s0 = mb & 2047;
#pragma unroll
      for (int nj = 0; nj < 2; nj++) {
        const int nn = n0 - 512 + wn * 32 + nj * 16 + lq;
        const int hh = nn >> 5, dd = nn & 31;
        uint2 pv;
        pv.x = pk2(fmaxf(acc[mi][nj][0], 0.f), fmaxf(acc[mi][nj][1], 0.f));
        pv.y = pk2(fmaxf(acc[mi][nj][2], 0.f), fmaxf(acc[mi][nj][3], 0.f));
        *(uint2*)(outVT + ((size_t)(bq * 8 + hh) * 32 + dd) * 2048 + s0) = pv;
      }
    }
  } else if (outB2 && n0 >= 256) {  // K path (fused QKV)
#pragma unroll
    for (int mi = 0; mi < 4; mi++) {
      const int m = m0 + wm * 64 + mi * 16 + kg * 4;
#pragma unroll
      for (int nj = 0; nj < 2; nj++) {
        const int nn = n0 - 256 + wn * 32 + nj * 16 + lq;
#pragma unroll
        for (int r = 0; r < 4; r++)
          outB2[(size_t)(m + r) * 256 + nn] = bf1(fmaxf(acc[mi][nj][r], 0.f));
      }
    }
  } else {
    const int ldo = (outB2 || outVT) ? 256 : N;  // fused-Q path uses 256
#pragma unroll
    for (int mi = 0; mi < 4; mi++) {
      const int m = m0 + wm * 64 + mi * 16 + kg * 4;
#pragma unroll
      for (int nj = 0; nj < 2; nj++) {
        const int n = n0 + wn * 32 + nj * 16 + lq;
#pragma unroll
        for (int r = 0; r < 4; r++) {
          float v = fmaxf(acc[mi][nj][r], 0.f);
          if (res) v += res[(size_t)(m + r) * N + n];
          if (outF) outF[(size_t)(m + r) * N + n] = v;
          if (outB) outB[(size_t)(m + r) * ldo + n] = bf1(v * bscale);
        }
      }
    }
  }
}

// ---------------- MFMA flash attention, fixed-base softmax ----------------
// 4 waves x 32 q rows (2 q-frags), 64 keys/step. K tile in LDS dbuf
// (gload_lds, swizzled source); V^T read DIRECTLY from global (L2-hot),
// 2-deep named-register prefetch. Zero-dest QK MFMA; native v_exp_f32.
// Permuted-K QK^T (P feeds PV in-register), KV-split2, fp32 partials.
__global__ __launch_bounds__(256) void attn_mfma_kernel(
    const unsigned short* __restrict__ Q, const unsigned short* __restrict__ K,
    const unsigned short* __restrict__ VT, float* __restrict__ oP,
    float* __restrict__ lP, int nkeys) {
  __shared__ alignas(16) unsigned short Ks[2][64 * 32];  // 8 KB dbuf

  const int tid = threadIdx.x;
  const int w = tid >> 6;
  const int lane = tid & 63;
  const int lq = lane & 15;
  const int kg = lane >> 4;
  const int bh = blockIdx.y, b = bh >> 3, h = bh & 7;
  const int p = blockIdx.z;
  const int q0 = blockIdx.x * 128 + w * 32;
  const size_t base = (size_t)b * SEQ * DMODEL + h * 32;

  u32x4 qf[2];
  qf[0] = *(const u32x4*)(Q + base + (size_t)(q0 + lq) * DMODEL + kg * 8);
  qf[1] = *(const u32x4*)(Q + base + (size_t)(q0 + 16 + lq) * DMODEL + kg * 8);

  f32x4 oLo[2] = {{0.f, 0.f, 0.f, 0.f}, {0.f, 0.f, 0.f, 0.f}};
  f32x4 oHi[2] = {{0.f, 0.f, 0.f, 0.f}, {0.f, 0.f, 0.f, 0.f}};
  f32x4 lac[2] = {{0.f, 0.f, 0.f, 0.f}, {0.f, 0.f, 0.f, 0.f}};
  const f32x4 zq = {0.f, 0.f, 0.f, 0.f};  // shared zero C operand
  const unsigned ONE2 = 0x3F803F80u;
  const u32x4 ones = {ONE2, ONE2, ONE2, ONE2};

  const int kg4 = (lane & 3) ^ ((lane >> 3) & 3);  // K src slot swizzle
  const unsigned short* vtb = VT + (size_t)bh * 32 * 2048;

  // Permuted ka rows (R11): PV B-operand assembles in-register.
  int krow[4], kslt[4];
#pragma unroll
  for (int s4 = 0; s4 < 4; s4++) {
    const int g = (s4 >> 1) * 32 + ((lq >> 2) << 3) + ((s4 & 1) << 2) + (lq & 3);
    krow[s4] = g;
    kslt[s4] = kg ^ ((g >> 1) & 3);
  }

  // V^T per-lane base pointers (16B contiguous per load, L2-resident).
  const unsigned short* vp0 = vtb + (size_t)lq * 2048 + kg * 8;
  const unsigned short* vp1 = vtb + (size_t)(16 + lq) * 2048 + kg * 8;

  auto STAGE = [&](int buf, int kt) {
    const int kr = w * 16 + (lane >> 2);
    gload_lds16(K + base + (size_t)(kt + kr) * DMODEL + kg4 * 8,
                (char*)Ks[buf] + w * 1024);
  };
  auto LOADV = [&](u32x4 (&va)[4], int kt) {
    va[0] = *(const u32x4*)(vp0 + kt);
    va[1] = *(const u32x4*)(vp0 + kt + 32);
    va[2] = *(const u32x4*)(vp1 + kt);
    va[3] = *(const u32x4*)(vp1 + kt + 32);
  };

  auto COMPUTE = [&](const unsigned short* ks, const u32x4 (&va)[4]) {
    u32x4 ka[4];
#pragma unroll
    for (int s4 = 0; s4 < 4; s4++)
      ka[s4] = *(const u32x4*)&ks[(krow[s4] << 5) + (kslt[s4] << 3)];

    f32x4 sc[2][4];
    __builtin_amdgcn_s_setprio(1);
#pragma unroll
    for (int f = 0; f < 2; f++)
#pragma unroll
      for (int s4 = 0; s4 < 4; s4++)
        sc[f][s4] = mfma_bf16_z(ka[s4], qf[f], zq);
    __builtin_amdgcn_s_setprio(0);

    // P = 2^sc via native v_exp_f32 (sc >= 0; base cancels in o/l)
    u32x4 pf0[2], pf1[2];
#pragma unroll
    for (int f = 0; f < 2; f++) {
      pf0[f][0] = pk2(fexp2(sc[f][0][0]), fexp2(sc[f][0][1]));
      pf0[f][1] = pk2(fexp2(sc[f][0][2]), fexp2(sc[f][0][3]));
      pf0[f][2] = pk2(fexp2(sc[f][1][0]), fexp2(sc[f][1][1]));
      pf0[f][3] = pk2(fexp2(sc[f][1][2]), fexp2(sc[f][1][3]));
      pf1[f][0] = pk2(fexp2(sc[f][2][0]), fexp2(sc[f][2][1]));
      pf1[f][1] = pk2(fexp2(sc[f][2][2]), fexp2(sc[f][2][3]));
      pf1[f][2] = pk2(fexp2(sc[f][3][0]), fexp2(sc[f][3][1]));
      pf1[f][3] = pk2(fexp2(sc[f][3][2]), fexp2(sc[f][3][3]));
    }

#pragma unroll
    for (int f = 0; f < 2; f++) {
      __builtin_amdgcn_s_setprio(1);
      oLo[f] = mfma_bf16(va[0], pf0[f], oLo[f]);
      oLo[f] = mfma_bf16(va[1], pf1[f], oLo[f]);
      oHi[f] = mfma_bf16(va[2], pf0[f], oHi[f]);
      oHi[f] = mfma_bf16(va[3], pf1[f], oHi[f]);
      lac[f] = mfma_bf16(ones, pf0[f], lac[f]);
      lac[f] = mfma_bf16(ones, pf1[f], lac[f]);
      __builtin_amdgcn_s_setprio(0);
    }
  };

  const int kbeg = p * nkeys;
  const int nt = nkeys >> 6;  // 16 (even)
  u32x4 vaA[4], vaB[4];
  STAGE(0, kbeg);
  LOADV(vaA, kbeg);
  for (int t = 0; t < nt; t += 2) {
    __syncthreads();  // K buf0 (tile t) ready
    if (t + 1 < nt) { STAGE(1, kbeg + (t + 1) * 64); LOADV(vaB, (t + 1) * 64); }
    COMPUTE(&Ks[0][0], vaA);
    __syncthreads();  // all waves done reading buf0; buf1 (t+1) ready next
    if (t + 2 < nt) { STAGE(0, kbeg + (t + 2) * 64); LOADV(vaA, (t + 2) * 64); }
    if (t + 1 < nt) COMPUTE(&Ks[1][0], vaB);
  }

  // Partials out: fp32 unnormalized o + l (fixed base -> combine sums)
#pragma unroll
  for (int f = 0; f < 2; f++) {
    const int qrow = q0 + f * 16 + lq;
    const size_t sidx = ((size_t)p * 32 + bh) * SEQ + qrow;
    if (kg == 0) lP[sidx] = lac[f][0];
    float* op = oP + sidx * 32;
    *(f32x4*)(op + kg * 4) = oLo[f];
    *(f32x4*)(op + 16 + kg * 4) = oHi[f];
  }
}

// Merge 2 partial states: out = (o0+o1) / (l0+l1), write bf16
__global__ __launch_bounds__(256) void attn_combine_kernel(
    const float* __restrict__ oP, const float* __restrict__ lP,
    unsigned short* __restrict__ O) {
  const int t = blockIdx.x * blockDim.x + threadIdx.x;
  const int bh = t >> 11;
  const int qrow = t & 2047;
  const int b = bh >> 3, h = bh & 7;

  const size_t s0 = (size_t)bh * SEQ + qrow;
  const size_t s1 = ((size_t)32 + bh) * SEQ + qrow;
  const float inv = 1.f / (lP[s0] + lP[s1]);

  const float* o0 = oP + s0 * 32;
  const float* o1 = oP + s1 * 32;
  unsigned short* outp =
      O + (size_t)b * SEQ * DMODEL + (size_t)qrow * DMODEL + h * 32;
#pragma unroll
  for (int i = 0; i < 8; i++) {
    float4 a = *(const float4*)(o0 + i * 4);
    float4 c = *(const float4*)(o1 + i * 4);
    uint2 v;
    v.x = pk2((a.x + c.x) * inv, (a.y + c.y) * inv);
    v.y = pk2((a.z + c.z) * inv, (a.w + c.w) * inv);
    *(uint2*)(outp + i * 4) = v;
  }
}

// ---------------- LayerNorm of relu(P0+P1)+res (split-K combine) --------
__global__ __launch_bounds__(256) void ln_fuse_kernel(
    const float* __restrict__ P0, const float* __restrict__ P1,
    const float* __restrict__ res, const float* __restrict__ g,
    const float* __restrict__ b, float* __restrict__ Y,
    unsigned short* __restrict__ Yb) {
  const int wid = (blockIdx.x * blockDim.x + threadIdx.x) >> 6;
  const int lane = threadIdx.x & 63;
  const size_t off = (size_t)wid * DMODEL + lane * 4;
  float4 p0 = *(const float4*)(P0 + off);
  float4 p1 = *(const float4*)(P1 + off);
  float4 r = *(const float4*)(res + off);
  float4 v;
  v.x = fmaxf(p0.x + p1.x, 0.f) + r.x;
  v.y = fmaxf(p0.y + p1.y, 0.f) + r.y;
  v.z = fmaxf(p0.z + p1.z, 0.f) + r.z;
  v.w = fmaxf(p0.w + p1.w, 0.f) + r.w;
  float s = v.x + v.y + v.z + v.w;
  float s2 = v.x * v.x + v.y * v.y + v.z * v.z + v.w * v.w;
#pragma unroll
  for (int o = 32; o >= 1; o >>= 1) {
    s += __shfl_xor(s, o, 64);
    s2 += __shfl_xor(s2, o, 64);
  }
  const float mu = s * (1.f / DMODEL);
  const float var = s2 * (1.f / DMODEL) - mu * mu;
  const float inv = rsqrtf(var + LN_EPS);
  float4 gv = *(const float4*)(g + lane * 4);
  float4 bv = *(const float4*)(b + lane * 4);
  float4 o;
  o.x = (v.x - mu) * inv * gv.x + bv.x;
  o.y = (v.y - mu) * inv * gv.y + bv.y;
  o.z = (v.z - mu) * inv * gv.z + bv.z;
  o.w = (v.w - mu) * inv * gv.w + bv.w;
  if (Y) *(float4*)(Y + off) = o;
  if (Yb) {
    uint2 pk;
    pk.x = pk2(o.x, o.y);
    pk.y = pk2(o.z, o.w);
    *(uint2*)(Yb + off) = pk;
  }
}

extern "C" void kernel_launch(void* const* d_in, const int* in_sizes, int n_in,
                              void* d_out, int out_size, void* d_ws, size_t ws_size,
                              hipStream_t stream) {
  const float* x = (const float*)d_in[0];
  const float* g1 = (const float*)d_in[13];
  const float* b1 = (const float*)d_in[14];
  const float* g2 = (const float*)d_in[15];
  const float* b2 = (const float*)d_in[16];
  const float* g3 = (const float*)d_in[17];
  const float* b3 = (const float*)d_in[18];
  const float* g4 = (const float*)d_in[19];
  const float* b4 = (const float*)d_in[20];

  float* out = (float*)d_out;
  float* ws = (float*)d_ws;
  const size_t NM = (size_t)MROWS * DMODEL;
  const size_t ML = (size_t)32 * SEQ;  // 65536 rows per split
  const float QSCALE = 0.17677669529663687f * 1.4426950408889634f;

  float* F0 = ws;                       // vt alias only
  float* F1 = ws + NM;                  // fp32 residual stream
  // union [2NM,4NM): fb bf16 8192x1024 (FFN) | attn oP fp32 | o-proj P0/P1
  char* U = (char*)(ws + 2 * NM);
  unsigned short* fb = (unsigned short*)U;
  float* oP = (float*)U;
  float* oprojP0 = (float*)U;
  float* oprojP1 = (float*)U + NM;
  float* lP = ws + 4 * NM;  // 2 x 65536 fp32
  unsigned short* xb = (unsigned short*)(lP + 2 * ML);
  unsigned short* qb = xb + NM;
  unsigned short* kb = qb + NM;
  unsigned short* ob = kb + NM;
  unsigned short* nb = ob + NM;
  unsigned short* wb = nb + NM;
  unsigned short* qkv1 = wb;
  unsigned short* qkv2 = wb + 3 * 65536;
  unsigned short* o1w = wb + 6 * 65536;
  unsigned short* o2w = wb + 7 * 65536;
  unsigned short* f11 = wb + 8 * 65536;
  unsigned short* f21 = f11 + 262144;
  unsigned short* f12 = f21 + 262144;
  unsigned short* f22 = f12 + 262144;
  unsigned short* vt = (unsigned short*)F0;   // aliases F0
  float* f2P0 = (float*)qb;  // qb+kb span = NM floats (dead after attn)
  float* f2P1 = (float*)ob;  // ob+nb span = NM floats (dead after f1)

  {
    CvtArgs a;
    a.s[0] = x; a.d[0] = xb; a.n4[0] = (int)(NM / 4);
    unsigned short* wd[12] = {qkv1, qkv1 + 65536, qkv1 + 131072, o1w,
                              qkv2, qkv2 + 65536, qkv2 + 131072, o2w,
                              f11, f21, f12, f22};
    for (int i = 0; i < 12; i++) {
      a.s[i + 1] = (const float*)d_in[i + 1];
      a.d[i + 1] = wd[i];
      a.n4[i + 1] = (i < 8) ? 65536 / 4 : 262144 / 4;
    }
    cvt_kernel<<<dim3(256, 13), 256, 0, stream>>>(a);
  }

  auto gemm = [&](const unsigned short* A, const unsigned short* W,
                  unsigned short* oB, unsigned short* oB2,
                  unsigned short* oVT, float bs, int N, int K) {
    const int ntx = N / 64;
    gemm_bf16_kernel<<<ntx * (MROWS / 128), 256, 0, stream>>>(
        A, W, nullptr, nullptr, oB, oB2, oVT, nullptr, nullptr, bs, N, K,
        ntx, 0);
  };
  auto gemm_split = [&](const unsigned short* A, const unsigned short* W,
                        float* P0, float* P1, int N, int K) {
    const int ntx = N / 64;
    gemm_bf16_kernel<<<ntx * (MROWS / 128) * 2, 256, 0, stream>>>(
        A, W, nullptr, nullptr, nullptr, nullptr, nullptr, P0, P1, 1.f, N, K,
        ntx, 1);
  };
  auto attn = [&](const unsigned short* Q, const unsigned short* K,
                  const unsigned short* VT, unsigned short* O) {
    attn_mfma_kernel<<<dim3(SEQ / 128, 32, 2), 256, 0, stream>>>(
        Q, K, VT, oP, lP, SEQ / 2);
    attn_combine_kernel<<<65536 / 256, 256, 0, stream>>>(oP, lP, O);
  };
  auto ln_fuse = [&](const float* P0, const float* P1, const float* res,
                     const float* gm, const float* bt, float* Y,
                     unsigned short* Yb) {
    ln_fuse_kernel<<<MROWS / 4, 256, 0, stream>>>(P0, P1, res, gm, bt, Y, Yb);
  };

  // ---- Block 1 ----
  gemm(xb, qkv1, qb, kb, vt, QSCALE, 768, 256);        // fused QKV
  attn(qb, kb, vt, ob);                                // -> ob (bf16)
  gemm_split(ob, o1w, oprojP0, oprojP1, 256, 256);     // o-proj partials
  ln_fuse(oprojP0, oprojP1, x, g1, b1, F1, nb);        // x1n = LN(relu+x)
  gemm(nb, f11, fb, nullptr, nullptr, 1.f, 1024, 256); // f (bf16)
  gemm_split(fb, f21, f2P0, f2P1, 256, 1024);          // f2 partials
  ln_fuse(f2P0, f2P1, F1, g2, b2, F1, xb);             // block1 out

  // ---- Block 2 ----
  gemm(xb, qkv2, qb, kb, vt, QSCALE, 768, 256);
  attn(qb, kb, vt, ob);
  gemm_split(ob, o2w, oprojP0, oprojP1, 256, 256);
  ln_fuse(oprojP0, oprojP1, F1, g3, b3, F1, nb);
  gemm(nb, f12, fb, nullptr, nullptr, 1.f, 1024, 256);
  gemm_split(fb, f22, f2P0, f2P1, 256, 1024);
  ln_fuse(f2P0, f2P1, F1, g4, b4, out, nullptr);
}

// Round 18
// 217.134 us; speedup vs baseline: 1.0238x; 1.0238x over previous
//
#include <hip/hip_runtime.h>
#include <hip/hip_bf16.h>

// Encoder: B=4, S=2048, D=256, H=8, DK=32, DFF=1024, fp32 in/out.
// bf16 pipeline. Fixed-base softmax (scores>=0: ReLU'd q,k), l via
// ones-MFMA. Attn: K LDS dbuf + V direct from L2 (kbeg FIXED) + native
// v_exp; KV-split4 with bf16 o-partials. GEMM: 64x64/4-wave dbuf (R15);
// N=256 GEMMs split-K=2 + fused relu+add+LN combine.

#define MROWS 8192   // B*S
#define DMODEL 256
#define SEQ 2048
#define LN_EPS 1e-5f

typedef float f32x4 __attribute__((ext_vector_type(4)));
typedef unsigned int u32x4 __attribute__((ext_vector_type(4)));

__device__ __forceinline__ unsigned pk2(float lo, float hi) {
  union { __hip_bfloat162 h; unsigned u; } c;
  c.h = __float22bfloat162_rn(make_float2(lo, hi));
  return c.u;
}
__device__ __forceinline__ unsigned short bf1(float f) {
  union { __hip_bfloat16 h; unsigned short u; } c;
  c.h = __float2bfloat16(f);
  return c.u;
}
__device__ __forceinline__ float b2f(unsigned short u) {
  union { unsigned u32; float f; } c;
  c.u32 = (unsigned)u << 16;
  return c.f;
}
// native 2^x: single v_exp_f32
__device__ __forceinline__ float fexp2(float x) {
  return __builtin_amdgcn_exp2f(x);
}

__device__ __forceinline__ f32x4 mfma_bf16(u32x4 a, u32x4 b, f32x4 c) {
  asm volatile("v_mfma_f32_16x16x32_bf16 %0, %1, %2, %0"
               : "+v"(c) : "v"(a), "v"(b));
  return c;
}
// zero-dest form: separate dest, shared read-only zero quad (no RMW copy)
__device__ __forceinline__ f32x4 mfma_bf16_z(u32x4 a, u32x4 b,
                                             const f32x4& z) {
  f32x4 d;
  asm volatile("v_mfma_f32_16x16x32_bf16 %0, %1, %2, %3"
               : "=v"(d) : "v"(a), "v"(b), "v"(z));
  return d;
}

__device__ __forceinline__ void gload_lds16(const void* g, void* l) {
  __builtin_amdgcn_global_load_lds(
      (const __attribute__((address_space(1))) void*)g,
      (__attribute__((address_space(3))) void*)l, 16, 0, 0);
}

// ---------------- fp32 -> bf16 batch convert ----------------
struct CvtArgs {
  const float* s[13];
  unsigned short* d[13];
  int n4[13];
};
__global__ __launch_bounds__(256) void cvt_kernel(CvtArgs a) {
  const int y = blockIdx.y;
  const int n4 = a.n4[y];
  const float4* src = (const float4*)a.s[y];
  unsigned short* dst = a.d[y];
  for (int i = blockIdx.x * 256 + threadIdx.x; i < n4; i += 256 * 256) {
    float4 v = src[i];
    uint2 o;
    o.x = pk2(v.x, v.y);
    o.y = pk2(v.z, v.w);
    *(uint2*)(dst + (size_t)i * 4) = o;
  }
}

// ---------------- bf16 MFMA GEMM: relu(A @ W^T) (+res) ----------------
// 256 threads, 4 waves (2x2), block 64x64, wave 32x32, BK=64, dbuf (R15).
// splitk: grid doubled, lid&1 = K-slice, raw fp32 partial -> outP0/P1.
// Fused-QKV epilogue: n0<256 -> outB (bscale), [256,512) -> outB2,
// >=512 -> outVT (V^T [b*8+h][d][s]). XCD-swizzled 1D grid.
__global__ __launch_bounds__(256) void gemm_bf16_kernel(
    const unsigned short* __restrict__ A, const unsigned short* __restrict__ W,
    const float* __restrict__ res, float* __restrict__ outF,
    unsigned short* __restrict__ outB, unsigned short* __restrict__ outB2,
    unsigned short* __restrict__ outVT, float* __restrict__ outP0,
    float* __restrict__ outP1, float bscale, int N, int K, int ntx,
    int splitk) {
  __shared__ alignas(16) unsigned short As[2][64 * 64];
  __shared__ alignas(16) unsigned short Ws[2][64 * 64];
  const int tid = threadIdx.x;
  const int w = tid >> 6, lane = tid & 63;
  const int lq = lane & 15, kg = lane >> 4;
  const int wm = w >> 1, wn = w & 1;
  const int nwg = gridDim.x, cpx = nwg >> 3, bid = blockIdx.x;
  int lid = (bid & 7) * cpx + (bid >> 3);
  int kslice = 0;
  if (splitk) { kslice = lid & 1; lid >>= 1; }
  const int m0 = (lid / ntx) * 64, n0 = (lid % ntx) * 64;
  const int klen = splitk ? (K >> 1) : K;
  const unsigned short* Ab = A + (size_t)kslice * (K >> 1);
  const unsigned short* Wb = W + (size_t)kslice * (K >> 1);

  f32x4 acc[2][2] = {};

  auto STAGE = [&](int buf, int k0) {
#pragma unroll
    for (int i = 0; i < 2; i++) {
      const int li = i * 256 + tid;
      const int row = li >> 3, sl = (li & 7) ^ (row & 7);
      gload_lds16(Ab + (size_t)(m0 + row) * K + k0 + sl * 8,
                  (char*)As[buf] + (i * 256 + (tid & ~63)) * 16);
    }
#pragma unroll
    for (int i = 0; i < 2; i++) {
      const int li = i * 256 + tid;
      const int row = li >> 3, sl = (li & 7) ^ (row & 7);
      gload_lds16(Wb + (size_t)(n0 + row) * K + k0 + sl * 8,
                  (char*)Ws[buf] + (i * 256 + (tid & ~63)) * 16);
    }
  };

  const int nt = klen >> 6;
  STAGE(0, 0);
  for (int t = 0; t < nt; t++) {
    __syncthreads();  // drains vmcnt: buf[t&1] ready
    if (t + 1 < nt) STAGE((t + 1) & 1, (t + 1) << 6);
    const unsigned short* as = As[t & 1];
    const unsigned short* wsb = Ws[t & 1];
#pragma unroll
    for (int kk = 0; kk < 2; kk++) {
      const int sl = (((kk * 4 + kg) ^ (lq & 7)) << 3);
      u32x4 a0 = *(const u32x4*)&as[((wm * 32 + lq) << 6) + sl];
      u32x4 a1 = *(const u32x4*)&as[((wm * 32 + 16 + lq) << 6) + sl];
      u32x4 b0 = *(const u32x4*)&wsb[((wn * 32 + lq) << 6) + sl];
      u32x4 b1 = *(const u32x4*)&wsb[((wn * 32 + 16 + lq) << 6) + sl];
      __builtin_amdgcn_s_setprio(1);
      acc[0][0] = mfma_bf16(a0, b0, acc[0][0]);
      acc[0][1] = mfma_bf16(a0, b1, acc[0][1]);
      acc[1][0] = mfma_bf16(a1, b0, acc[1][0]);
      acc[1][1] = mfma_bf16(a1, b1, acc[1][1]);
      __builtin_amdgcn_s_setprio(0);
    }
  }

  // Epilogue: D row = kg*4+r, col = lq per 16x16 frag.
  if (splitk) {  // raw fp32 partial (no relu, no res)
    float* P = kslice ? outP1 : outP0;
#pragma unroll
    for (int mi = 0; mi < 2; mi++) {
      const int m = m0 + wm * 32 + mi * 16 + kg * 4;
#pragma unroll
      for (int nj = 0; nj < 2; nj++) {
        const int n = n0 + wn * 32 + nj * 16 + lq;
#pragma unroll
        for (int r = 0; r < 4; r++)
          P[(size_t)(m + r) * N + n] = acc[mi][nj][r];
      }
    }
  } else if (outVT && n0 >= 512) {  // V^T path (fused QKV)
#pragma unroll
    for (int mi = 0; mi < 2; mi++) {
      const int mb = m0 + wm * 32 + mi * 16 + kg * 4;
      const int bq = mb >> 11, s0 = mb & 2047;
#pragma unroll
      for (int nj = 0; nj < 2; nj++) {
        const int nn = n0 - 512 + wn * 32 + nj * 16 + lq;
        const int hh = nn >> 5, dd = nn & 31;
        uint2 pv;
        pv.x = pk2(fmaxf(acc[mi][nj][0], 0.f), fmaxf(acc[mi][nj][1], 0.f));
        pv.y = pk2(fmaxf(acc[mi][nj][2], 0.f), fmaxf(acc[mi][nj][3], 0.f));
        *(uint2*)(outVT + ((size_t)(bq * 8 + hh) * 32 + dd) * 2048 + s0) = pv;
      }
    }
  } else if (outB2 && n0 >= 256) {  // K path (fused QKV)
#pragma unroll
    for (int mi = 0; mi < 2; mi++) {
      const int m = m0 + wm * 32 + mi * 16 + kg * 4;
#pragma unroll
      for (int nj = 0; nj < 2; nj++) {
        const int nn = n0 - 256 + wn * 32 + nj * 16 + lq;
#pragma unroll
        for (int r = 0; r < 4; r++)
          outB2[(size_t)(m + r) * 256 + nn] = bf1(fmaxf(acc[mi][nj][r], 0.f));
      }
    }
  } else {
    const int ldo = (outB2 || outVT) ? 256 : N;  // fused-Q path uses 256
#pragma unroll
    for (int mi = 0; mi < 2; mi++) {
      const int m = m0 + wm * 32 + mi * 16 + kg * 4;
#pragma unroll
      for (int nj = 0; nj < 2; nj++) {
        const int n = n0 + wn * 32 + nj * 16 + lq;
#pragma unroll
        for (int r = 0; r < 4; r++) {
          float v = fmaxf(acc[mi][nj][r], 0.f);
          if (res) v += res[(size_t)(m + r) * N + n];
          if (outF) outF[(size_t)(m + r) * N + n] = v;
          if (outB) outB[(size_t)(m + r) * ldo + n] = bf1(v * bscale);
        }
      }
    }
  }
}

// ---------------- MFMA flash attention, fixed-base softmax ----------------
// 4 waves x 32 q rows (2 q-frags), 64 keys/step. K tile in LDS dbuf
// (gload_lds, swizzled source); V^T read DIRECTLY from global (L2-hot,
// kbeg-corrected), 2-deep named-register prefetch. Zero-dest QK MFMA;
// native v_exp_f32. Permuted-K QK^T (P feeds PV in-register), KV-split4,
// bf16 unnormalized o + fp32 l partials.
__global__ __launch_bounds__(256) void attn_mfma_kernel(
    const unsigned short* __restrict__ Q, const unsigned short* __restrict__ K,
    const unsigned short* __restrict__ VT, unsigned short* __restrict__ oPb,
    float* __restrict__ lP, int nkeys) {
  __shared__ alignas(16) unsigned short Ks[2][64 * 32];  // 8 KB dbuf

  const int tid = threadIdx.x;
  const int w = tid >> 6;
  const int lane = tid & 63;
  const int lq = lane & 15;
  const int kg = lane >> 4;
  const int bh = blockIdx.y, b = bh >> 3, h = bh & 7;
  const int p = blockIdx.z;
  const int q0 = blockIdx.x * 128 + w * 32;
  const size_t base = (size_t)b * SEQ * DMODEL + h * 32;

  u32x4 qf[2];
  qf[0] = *(const u32x4*)(Q + base + (size_t)(q0 + lq) * DMODEL + kg * 8);
  qf[1] = *(const u32x4*)(Q + base + (size_t)(q0 + 16 + lq) * DMODEL + kg * 8);

  f32x4 oLo[2] = {{0.f, 0.f, 0.f, 0.f}, {0.f, 0.f, 0.f, 0.f}};
  f32x4 oHi[2] = {{0.f, 0.f, 0.f, 0.f}, {0.f, 0.f, 0.f, 0.f}};
  f32x4 lac[2] = {{0.f, 0.f, 0.f, 0.f}, {0.f, 0.f, 0.f, 0.f}};
  const f32x4 zq = {0.f, 0.f, 0.f, 0.f};  // shared zero C operand
  const unsigned ONE2 = 0x3F803F80u;
  const u32x4 ones = {ONE2, ONE2, ONE2, ONE2};

  const int kg4 = (lane & 3) ^ ((lane >> 3) & 3);  // K src slot swizzle
  const unsigned short* vtb = VT + (size_t)bh * 32 * 2048;

  // Permuted ka rows (R11): PV B-operand assembles in-register.
  int krow[4], kslt[4];
#pragma unroll
  for (int s4 = 0; s4 < 4; s4++) {
    const int g = (s4 >> 1) * 32 + ((lq >> 2) << 3) + ((s4 & 1) << 2) + (lq & 3);
    krow[s4] = g;
    kslt[s4] = kg ^ ((g >> 1) & 3);
  }

  // V^T per-lane base pointers (16B contiguous per load, L2-resident).
  const unsigned short* vp0 = vtb + (size_t)lq * 2048 + kg * 8;
  const unsigned short* vp1 = vtb + (size_t)(16 + lq) * 2048 + kg * 8;

  auto STAGE = [&](int buf, int kt) {
    const int kr = w * 16 + (lane >> 2);
    gload_lds16(K + base + (size_t)(kt + kr) * DMODEL + kg4 * 8,
                (char*)Ks[buf] + w * 1024);
  };
  auto LOADV = [&](u32x4 (&va)[4], int kt) {  // kt = GLOBAL key offset
    va[0] = *(const u32x4*)(vp0 + kt);
    va[1] = *(const u32x4*)(vp0 + kt + 32);
    va[2] = *(const u32x4*)(vp1 + kt);
    va[3] = *(const u32x4*)(vp1 + kt + 32);
  };

  auto COMPUTE = [&](const unsigned short* ks, const u32x4 (&va)[4]) {
    u32x4 ka[4];
#pragma unroll
    for (int s4 = 0; s4 < 4; s4++)
      ka[s4] = *(const u32x4*)&ks[(krow[s4] << 5) + (kslt[s4] << 3)];

    f32x4 sc[2][4];
    __builtin_amdgcn_s_setprio(1);
#pragma unroll
    for (int f = 0; f < 2; f++)
#pragma unroll
      for (int s4 = 0; s4 < 4; s4++)
        sc[f][s4] = mfma_bf16_z(ka[s4], qf[f], zq);
    __builtin_amdgcn_s_setprio(0);

    // P = 2^sc via native v_exp_f32 (sc >= 0; base cancels in o/l)
    u32x4 pf0[2], pf1[2];
#pragma unroll
    for (int f = 0; f < 2; f++) {
      pf0[f][0] = pk2(fexp2(sc[f][0][0]), fexp2(sc[f][0][1]));
      pf0[f][1] = pk2(fexp2(sc[f][0][2]), fexp2(sc[f][0][3]));
      pf0[f][2] = pk2(fexp2(sc[f][1][0]), fexp2(sc[f][1][1]));
      pf0[f][3] = pk2(fexp2(sc[f][1][2]), fexp2(sc[f][1][3]));
      pf1[f][0] = pk2(fexp2(sc[f][2][0]), fexp2(sc[f][2][1]));
      pf1[f][1] = pk2(fexp2(sc[f][2][2]), fexp2(sc[f][2][3]));
      pf1[f][2] = pk2(fexp2(sc[f][3][0]), fexp2(sc[f][3][1]));
      pf1[f][3] = pk2(fexp2(sc[f][3][2]), fexp2(sc[f][3][3]));
    }

#pragma unroll
    for (int f = 0; f < 2; f++) {
      __builtin_amdgcn_s_setprio(1);
      oLo[f] = mfma_bf16(va[0], pf0[f], oLo[f]);
      oLo[f] = mfma_bf16(va[1], pf1[f], oLo[f]);
      oHi[f] = mfma_bf16(va[2], pf0[f], oHi[f]);
      oHi[f] = mfma_bf16(va[3], pf1[f], oHi[f]);
      lac[f] = mfma_bf16(ones, pf0[f], lac[f]);
      lac[f] = mfma_bf16(ones, pf1[f], lac[f]);
      __builtin_amdgcn_s_setprio(0);
    }
  };

  const int kbeg = p * nkeys;
  const int nt = nkeys >> 6;  // 8 (even)
  u32x4 vaA[4], vaB[4];
  STAGE(0, kbeg);
  LOADV(vaA, kbeg);
  for (int t = 0; t < nt; t += 2) {
    __syncthreads();  // K buf0 (tile t) ready
    if (t + 1 < nt) {
      STAGE(1, kbeg + (t + 1) * 64);
      LOADV(vaB, kbeg + (t + 1) * 64);
    }
    COMPUTE(&Ks[0][0], vaA);
    __syncthreads();  // all waves done reading buf0; buf1 (t+1) ready next
    if (t + 2 < nt) {
      STAGE(0, kbeg + (t + 2) * 64);
      LOADV(vaA, kbeg + (t + 2) * 64);
    }
    if (t + 1 < nt) COMPUTE(&Ks[1][0], vaB);
  }

  // Partials out: bf16 unnormalized o + fp32 l (fixed base -> combine sums)
#pragma unroll
  for (int f = 0; f < 2; f++) {
    const int qrow = q0 + f * 16 + lq;
    const size_t sidx = ((size_t)p * 32 + bh) * SEQ + qrow;
    if (kg == 0) lP[sidx] = lac[f][0];
    unsigned short* op = oPb + sidx * 32;
    uint2 lo, hi;
    lo.x = pk2(oLo[f][0], oLo[f][1]);
    lo.y = pk2(oLo[f][2], oLo[f][3]);
    hi.x = pk2(oHi[f][0], oHi[f][1]);
    hi.y = pk2(oHi[f][2], oHi[f][3]);
    *(uint2*)(op + kg * 4) = lo;
    *(uint2*)(op + 16 + kg * 4) = hi;
  }
}

// Merge 4 partial states: out = sum(o_p) / sum(l_p), bf16 in/out
__global__ __launch_bounds__(256) void attn_combine_kernel(
    const unsigned short* __restrict__ oPb, const float* __restrict__ lP,
    unsigned short* __restrict__ O) {
  const int t = blockIdx.x * blockDim.x + threadIdx.x;
  const int bh = t >> 11;
  const int qrow = t & 2047;
  const int b = bh >> 3, h = bh & 7;

  float lsum = 0.f;
#pragma unroll
  for (int pp = 0; pp < 4; pp++)
    lsum += lP[((size_t)pp * 32 + bh) * SEQ + qrow];
  const float inv = 1.f / lsum;

  float acc[32] = {};
#pragma unroll
  for (int pp = 0; pp < 4; pp++) {
    const unsigned short* op =
        oPb + (((size_t)pp * 32 + bh) * SEQ + qrow) * 32;
#pragma unroll
    for (int i = 0; i < 4; i++) {
      uint4 v = *(const uint4*)(op + i * 8);
      acc[i * 8 + 0] += b2f((unsigned short)(v.x & 0xffff));
      acc[i * 8 + 1] += b2f((unsigned short)(v.x >> 16));
      acc[i * 8 + 2] += b2f((unsigned short)(v.y & 0xffff));
      acc[i * 8 + 3] += b2f((unsigned short)(v.y >> 16));
      acc[i * 8 + 4] += b2f((unsigned short)(v.z & 0xffff));
      acc[i * 8 + 5] += b2f((unsigned short)(v.z >> 16));
      acc[i * 8 + 6] += b2f((unsigned short)(v.w & 0xffff));
      acc[i * 8 + 7] += b2f((unsigned short)(v.w >> 16));
    }
  }
  unsigned short* outp =
      O + (size_t)b * SEQ * DMODEL + (size_t)qrow * DMODEL + h * 32;
#pragma unroll
  for (int i = 0; i < 8; i++) {
    uint2 v;
    v.x = pk2(acc[i * 4 + 0] * inv, acc[i * 4 + 1] * inv);
    v.y = pk2(acc[i * 4 + 2] * inv, acc[i * 4 + 3] * inv);
    *(uint2*)(outp + i * 4) = v;
  }
}

// ---------------- LayerNorm of relu(P0+P1)+res (split-K combine) --------
__global__ __launch_bounds__(256) void ln_fuse_kernel(
    const float* __restrict__ P0, const float* __restrict__ P1,
    const float* __restrict__ res, const float* __restrict__ g,
    const float* __restrict__ b, float* __restrict__ Y,
    unsigned short* __restrict__ Yb) {
  const int wid = (blockIdx.x * blockDim.x + threadIdx.x) >> 6;
  const int lane = threadIdx.x & 63;
  const size_t off = (size_t)wid * DMODEL + lane * 4;
  float4 p0 = *(const float4*)(P0 + off);
  float4 p1 = *(const float4*)(P1 + off);
  float4 r = *(const float4*)(res + off);
  float4 v;
  v.x = fmaxf(p0.x + p1.x, 0.f) + r.x;
  v.y = fmaxf(p0.y + p1.y, 0.f) + r.y;
  v.z = fmaxf(p0.z + p1.z, 0.f) + r.z;
  v.w = fmaxf(p0.w + p1.w, 0.f) + r.w;
  float s = v.x + v.y + v.z + v.w;
  float s2 = v.x * v.x + v.y * v.y + v.z * v.z + v.w * v.w;
#pragma unroll
  for (int o = 32; o >= 1; o >>= 1) {
    s += __shfl_xor(s, o, 64);
    s2 += __shfl_xor(s2, o, 64);
  }
  const float mu = s * (1.f / DMODEL);
  const float var = s2 * (1.f / DMODEL) - mu * mu;
  const float inv = rsqrtf(var + LN_EPS);
  float4 gv = *(const float4*)(g + lane * 4);
  float4 bv = *(const float4*)(b + lane * 4);
  float4 o;
  o.x = (v.x - mu) * inv * gv.x + bv.x;
  o.y = (v.y - mu) * inv * gv.y + bv.y;
  o.z = (v.z - mu) * inv * gv.z + bv.z;
  o.w = (v.w - mu) * inv * gv.w + bv.w;
  if (Y) *(float4*)(Y + off) = o;
  if (Yb) {
    uint2 pk;
    pk.x = pk2(o.x, o.y);
    pk.y = pk2(o.z, o.w);
    *(uint2*)(Yb + off) = pk;
  }
}

extern "C" void kernel_launch(void* const* d_in, const int* in_sizes, int n_in,
                              void* d_out, int out_size, void* d_ws, size_t ws_size,
                              hipStream_t stream) {
  const float* x = (const float*)d_in[0];
  const float* g1 = (const float*)d_in[13];
  const float* b1 = (const float*)d_in[14];
  const float* g2 = (const float*)d_in[15];
  const float* b2 = (const float*)d_in[16];
  const float* g3 = (const float*)d_in[17];
  const float* b3 = (const float*)d_in[18];
  const float* g4 = (const float*)d_in[19];
  const float* b4 = (const float*)d_in[20];

  float* out = (float*)d_out;
  float* ws = (float*)d_ws;
  const size_t NM = (size_t)MROWS * DMODEL;
  const size_t ML = (size_t)32 * SEQ;  // 65536 rows per split
  const float QSCALE = 0.17677669529663687f * 1.4426950408889634f;

  float* F0 = ws;                       // vt alias only
  float* F1 = ws + NM;                  // fp32 residual stream
  // union [2NM,4NM): fb bf16 8192x1024 (FFN) | attn oPb bf16 4 splits
  //                 | o-proj/f2 split-K fp32 partials
  char* U = (char*)(ws + 2 * NM);
  unsigned short* fb = (unsigned short*)U;
  unsigned short* oPb = (unsigned short*)U;
  float* oprojP0 = (float*)U;
  float* oprojP1 = (float*)U + NM;
  float* lP = ws + 4 * NM;  // 4 x 65536 fp32
  unsigned short* xb = (unsigned short*)(lP + 4 * ML);
  unsigned short* qb = xb + NM;
  unsigned short* kb = qb + NM;
  unsigned short* ob = kb + NM;
  unsigned short* nb = ob + NM;
  unsigned short* wb = nb + NM;
  unsigned short* qkv1 = wb;
  unsigned short* qkv2 = wb + 3 * 65536;
  unsigned short* o1w = wb + 6 * 65536;
  unsigned short* o2w = wb + 7 * 65536;
  unsigned short* f11 = wb + 8 * 65536;
  unsigned short* f21 = f11 + 262144;
  unsigned short* f12 = f21 + 262144;
  unsigned short* f22 = f12 + 262144;
  unsigned short* vt = (unsigned short*)F0;   // aliases F0
  float* f2P0 = (float*)qb;  // qb+kb span = NM floats (dead after attn)
  float* f2P1 = (float*)ob;  // ob+nb span = NM floats (dead after f1)

  {
    CvtArgs a;
    a.s[0] = x; a.d[0] = xb; a.n4[0] = (int)(NM / 4);
    unsigned short* wd[12] = {qkv1, qkv1 + 65536, qkv1 + 131072, o1w,
                              qkv2, qkv2 + 65536, qkv2 + 131072, o2w,
                              f11, f21, f12, f22};
    for (int i = 0; i < 12; i++) {
      a.s[i + 1] = (const float*)d_in[i + 1];
      a.d[i + 1] = wd[i];
      a.n4[i + 1] = (i < 8) ? 65536 / 4 : 262144 / 4;
    }
    cvt_kernel<<<dim3(256, 13), 256, 0, stream>>>(a);
  }

  auto gemm = [&](const unsigned short* A, const unsigned short* W,
                  unsigned short* oB, unsigned short* oB2,
                  unsigned short* oVT, float bs, int N, int K) {
    const int ntx = N / 64;
    gemm_bf16_kernel<<<ntx * (MROWS / 64), 256, 0, stream>>>(
        A, W, nullptr, nullptr, oB, oB2, oVT, nullptr, nullptr, bs, N, K,
        ntx, 0);
  };
  auto gemm_split = [&](const unsigned short* A, const unsigned short* W,
                        float* P0, float* P1, int N, int K) {
    const int ntx = N / 64;
    gemm_bf16_kernel<<<ntx * (MROWS / 64) * 2, 256, 0, stream>>>(
        A, W, nullptr, nullptr, nullptr, nullptr, nullptr, P0, P1, 1.f, N, K,
        ntx, 1);
  };
  auto attn = [&](const unsigned short* Q, const unsigned short* K,
                  const unsigned short* VT, unsigned short* O) {
    attn_mfma_kernel<<<dim3(SEQ / 128, 32, 4), 256, 0, stream>>>(
        Q, K, VT, oPb, lP, SEQ / 4);
    attn_combine_kernel<<<65536 / 256, 256, 0, stream>>>(oPb, lP, O);
  };
  auto ln_fuse = [&](const float* P0, const float* P1, const float* res,
                     const float* gm, const float* bt, float* Y,
                     unsigned short* Yb) {
    ln_fuse_kernel<<<MROWS / 4, 256, 0, stream>>>(P0, P1, res, gm, bt, Y, Yb);
  };

  // ---- Block 1 ----
  gemm(xb, qkv1, qb, kb, vt, QSCALE, 768, 256);        // fused QKV
  attn(qb, kb, vt, ob);                                // -> ob (bf16)
  gemm_split(ob, o1w, oprojP0, oprojP1, 256, 256);     // o-proj partials
  ln_fuse(oprojP0, oprojP1, x, g1, b1, F1, nb);        // x1n = LN(relu+x)
  gemm(nb, f11, fb, nullptr, nullptr, 1.f, 1024, 256); // f (bf16)
  gemm_split(fb, f21, f2P0, f2P1, 256, 1024);          // f2 partials
  ln_fuse(f2P0, f2P1, F1, g2, b2, F1, xb);             // block1 out

  // ---- Block 2 ----
  gemm(xb, qkv2, qb, kb, vt, QSCALE, 768, 256);
  attn(qb, kb, vt, ob);
  gemm_split(ob, o2w, oprojP0, oprojP1, 256, 256);
  ln_fuse(oprojP0, oprojP1, F1, g3, b3, F1, nb);
  gemm(nb, f12, fb, nullptr, nullptr, 1.f, 1024, 256);
  gemm_split(fb, f22, f2P0, f2P1, 256, 1024);
  ln_fuse(f2P0, f2P1, F1, g4, b4, out, nullptr);
}